// Round 2
// baseline (1325.799 us; speedup 1.0000x reference)
//
#include <hip/hip_runtime.h>

typedef unsigned short u16;
typedef unsigned int u32;
typedef __bf16 bf16x8 __attribute__((ext_vector_type(8)));
typedef float floatx4 __attribute__((ext_vector_type(4)));
typedef u16 u16x4 __attribute__((ext_vector_type(4)));
typedef u16 u16x8 __attribute__((ext_vector_type(8)));

#define B_ 4
#define T_ 1024
#define C_ 2048
#define H_ 32
#define HD_ 64

__device__ __forceinline__ float b2f(u16 u) {
    u32 x = ((u32)u) << 16;
    return __builtin_bit_cast(float, x);
}
__device__ __forceinline__ u16 f2b(float f) {
    u32 i = __builtin_bit_cast(u32, f);
    u32 r = (i + 0x7FFFu + ((i >> 16) & 1u)) >> 16;   // round-nearest-even
    return (u16)r;
}

// ---------------------------------------------------------------------------
// GEMM: C[m,n] = sum_k A[m,k] * W[n,k] + bias[n]
//   W is fp32 (N x K), converted to bf16 during LDS staging.
//   MODE 0: A = x fp32 (4096 x 2048); epilogue: bias + RoPE + scatter to
//           q/k/v in (B,H,T,hd) bf16.
//   MODE 1: A = ctx bf16 (4096 x 2048); epilogue: bias, fp32 row-major store.
// 128x128 tile, BK=64, 4 waves x (4x4) mfma_f32_16x16x32_bf16 fragments.
// ---------------------------------------------------------------------------
template <int MODE>
__global__ __launch_bounds__(256) void gemm_bt(const void* __restrict__ Av,
                                               const float* __restrict__ W,
                                               const float* __restrict__ bias,
                                               const float* __restrict__ rope,
                                               void* __restrict__ o0v,
                                               u16* __restrict__ o1,
                                               u16* __restrict__ o2) {
    const int Kdim = 2048;
    __shared__ __align__(16) u16 As[128 * 64];
    __shared__ __align__(16) u16 Bs[128 * 64];

    const int tid = threadIdx.x;
    const int w = tid >> 6, lane = tid & 63;
    const int wr = w >> 1, wc = w & 1;
    const int quad = lane >> 4, l15 = lane & 15;
    const int mBase = blockIdx.y * 128, nBase = blockIdx.x * 128;

    floatx4 acc[4][4] = {};

    for (int k0 = 0; k0 < Kdim; k0 += 64) {
        // --- stage A tile (128 rows x 64 cols) into As as bf16 ---
        if (MODE == 0) {
            const float* Af = (const float*)Av;
#pragma unroll
            for (int p = 0; p < 8; p++) {
                const int idx = p * 1024 + tid * 4;
                const int row = idx >> 6, col = idx & 63;
                const floatx4 v = *(const floatx4*)(Af + (size_t)(mBase + row) * Kdim + k0 + col);
                const u16x4 h = {f2b(v.x), f2b(v.y), f2b(v.z), f2b(v.w)};
                *(u16x4*)&As[row * 64 + col] = h;
            }
        } else {
            const u16* Ab = (const u16*)Av;
#pragma unroll
            for (int p = 0; p < 4; p++) {
                const int idx = p * 2048 + tid * 8;
                const int row = idx >> 6, col = idx & 63;
                *(u16x8*)&As[row * 64 + col] =
                    *(const u16x8*)(Ab + (size_t)(mBase + row) * Kdim + k0 + col);
            }
        }
        // --- stage W tile (fp32 -> bf16) into Bs ---
#pragma unroll
        for (int p = 0; p < 8; p++) {
            const int idx = p * 1024 + tid * 4;
            const int row = idx >> 6, col = idx & 63;
            const floatx4 v = *(const floatx4*)(W + (size_t)(nBase + row) * Kdim + k0 + col);
            const u16x4 h = {f2b(v.x), f2b(v.y), f2b(v.z), f2b(v.w)};
            *(u16x4*)&Bs[row * 64 + col] = h;
        }
        __syncthreads();

#pragma unroll
        for (int ks = 0; ks < 64; ks += 32) {
            bf16x8 af[4], bfr[4];
#pragma unroll
            for (int i = 0; i < 4; i++)
                af[i] = *(const bf16x8*)&As[(wr * 64 + i * 16 + l15) * 64 + ks + quad * 8];
#pragma unroll
            for (int j = 0; j < 4; j++)
                bfr[j] = *(const bf16x8*)&Bs[(wc * 64 + j * 16 + l15) * 64 + ks + quad * 8];
#pragma unroll
            for (int i = 0; i < 4; i++)
#pragma unroll
                for (int j = 0; j < 4; j++)
                    acc[i][j] = __builtin_amdgcn_mfma_f32_16x16x32_bf16(af[i], bfr[j], acc[i][j], 0, 0, 0);
        }
        __syncthreads();
    }

    // epilogue: C/D layout col = lane&15 (per j-frag), row = quad*4 + reg (per i-frag)
    const int nq = nBase + wc * 64;
    float bv[4];
#pragma unroll
    for (int j = 0; j < 4; j++) bv[j] = bias[nq + j * 16 + l15];

    if (MODE == 0) {
        const int region = nq >> 11;            // 0=q 1=k 2=v (tile never straddles)
        const int h = (nq & 2047) >> 6;
        const int d = l15;                      // rope freq index (cols 0..15 pair with 16..31)
        u16* dst = (region == 0) ? (u16*)o0v : ((region == 1) ? o1 : o2);
#pragma unroll
        for (int i = 0; i < 4; i++) {
#pragma unroll
            for (int r = 0; r < 4; r++) {
                const int m = mBase + wr * 64 + i * 16 + quad * 4 + r;
                const int b = m >> 10, t = m & 1023;
                float v0 = acc[i][0][r] + bv[0];
                float v1 = acc[i][1][r] + bv[1];
                float v2 = acc[i][2][r] + bv[2];
                float v3 = acc[i][3][r] + bv[3];
                const size_t base = ((size_t)(b * H_ + h) * T_ + t) * HD_;
                if (region < 2) {
                    const float cz = rope[t * 32 + d * 2];
                    const float sz = rope[t * 32 + d * 2 + 1];
                    const float n0 = v0 * cz - v1 * sz;
                    const float n1 = v1 * cz + v0 * sz;
                    dst[base + d] = f2b(n0);
                    dst[base + 16 + d] = f2b(n1);
                } else {
                    dst[base + d] = f2b(v0);
                    dst[base + 16 + d] = f2b(v1);
                }
                dst[base + 32 + d] = f2b(v2);
                dst[base + 48 + d] = f2b(v3);
            }
        }
    } else {
        float* outf = (float*)o0v;
#pragma unroll
        for (int i = 0; i < 4; i++)
#pragma unroll
            for (int r = 0; r < 4; r++) {
                const int m = mBase + wr * 64 + i * 16 + quad * 4 + r;
                const size_t o = (size_t)m * 2048 + nq;
#pragma unroll
                for (int j = 0; j < 4; j++)
                    outf[o + j * 16 + l15] = acc[i][j][r] + bv[j];
            }
    }
}

// ---------------------------------------------------------------------------
// Flash-style causal attention. One block = one (b,h) x 64-query tile.
// q/k/v in (B,H,T,hd) bf16. Online softmax, fp32 accumulation.
// Thread (rg = tid&15, cg = tid>>4): owns rows rg+16i, S-cols cg+16j,
// O-dims cg*4..+3.
// ---------------------------------------------------------------------------
#define KV_STR 68
#define PS_STR 65

__global__ __launch_bounds__(256) void attn_kernel(const u16* __restrict__ qT,
                                                   const u16* __restrict__ kT,
                                                   const u16* __restrict__ vT,
                                                   u16* __restrict__ ctx) {
    __shared__ __align__(16) float Ks[64 * KV_STR];
    __shared__ __align__(16) float Vs[64 * KV_STR];
    __shared__ __align__(16) float Ps[64 * PS_STR];
    __shared__ __align__(16) u16 Qs[64 * KV_STR];
    __shared__ float m_s[64], l_s[64], alpha_s[64];

    const int tid = threadIdx.x;
    const int qt = (int)gridDim.x - 1 - (int)blockIdx.x;  // big tiles dispatch first
    const int bh = blockIdx.y;
    const size_t headBase = (size_t)bh * (T_ * HD_);
    const u16* qp = qT + headBase + (size_t)qt * 64 * HD_;

#pragma unroll
    for (int idx = tid * 4; idx < 4096; idx += 1024) {
        const int row = idx >> 6, col = idx & 63;
        *(u16x4*)&Qs[row * KV_STR + col] = *(const u16x4*)(qp + idx);
    }
    if (tid < 64) { m_s[tid] = -1e30f; l_s[tid] = 0.f; }

    const int rg = tid & 15, cg = tid >> 4;
    const int d0 = cg * 4;
    floatx4 acc[4] = {};

    for (int kt = 0; kt <= qt; kt++) {
        __syncthreads();  // prev PV done before K/V/P overwrite; 1st iter: Q/m/l visible
        const u16* kp = kT + headBase + (size_t)kt * 4096;
        const u16* vp = vT + headBase + (size_t)kt * 4096;
#pragma unroll
        for (int idx = tid * 4; idx < 4096; idx += 1024) {
            const int row = idx >> 6, col = idx & 63;
            const u16x4 ku = *(const u16x4*)(kp + idx);
            const u16x4 vu = *(const u16x4*)(vp + idx);
            const floatx4 kf = {b2f(ku.x), b2f(ku.y), b2f(ku.z), b2f(ku.w)};
            const floatx4 vf = {b2f(vu.x), b2f(vu.y), b2f(vu.z), b2f(vu.w)};
            *(floatx4*)&Ks[row * KV_STR + col] = kf;
            *(floatx4*)&Vs[row * KV_STR + col] = vf;
        }
        __syncthreads();

        // S = Q K^T
        float s[4][4] = {};
#pragma unroll 4
        for (int dd = 0; dd < 64; dd += 4) {
            floatx4 kv[4];
#pragma unroll
            for (int j = 0; j < 4; j++) kv[j] = *(const floatx4*)&Ks[(cg + 16 * j) * KV_STR + dd];
#pragma unroll
            for (int i = 0; i < 4; i++) {
                const u16x4 qu = *(const u16x4*)&Qs[(rg + 16 * i) * KV_STR + dd];
                const float q0 = b2f(qu.x), q1 = b2f(qu.y), q2 = b2f(qu.z), q3 = b2f(qu.w);
#pragma unroll
                for (int j = 0; j < 4; j++)
                    s[i][j] += q0 * kv[j].x + q1 * kv[j].y + q2 * kv[j].z + q3 * kv[j].w;
            }
        }
#pragma unroll
        for (int i = 0; i < 4; i++)
#pragma unroll
            for (int j = 0; j < 4; j++) {
                float sv = s[i][j] * 0.125f;  // 1/sqrt(64)
                if (kt * 64 + cg + 16 * j > qt * 64 + rg + 16 * i) sv = -1e30f;  // causal
                Ps[(rg + 16 * i) * PS_STR + cg + 16 * j] = sv;
            }
        __syncthreads();

        // online softmax, one thread per row
        if (tid < 64) {
            const int r = tid;
            float tmax = -1e30f;
#pragma unroll 8
            for (int c = 0; c < 64; c++) tmax = fmaxf(tmax, Ps[r * PS_STR + c]);
            const float mold = m_s[r];
            const float mnew = fmaxf(mold, tmax);
            const float alpha = __expf(mold - mnew);
            float sum = 0.f;
#pragma unroll 8
            for (int c = 0; c < 64; c++) {
                const float p = __expf(Ps[r * PS_STR + c] - mnew);
                Ps[r * PS_STR + c] = p;
                sum += p;
            }
            l_s[r] = l_s[r] * alpha + sum;
            m_s[r] = mnew;
            alpha_s[r] = alpha;
        }
        __syncthreads();

        // O = O*alpha + P V
#pragma unroll
        for (int i = 0; i < 4; i++) acc[i] *= alpha_s[rg + 16 * i];
#pragma unroll 8
        for (int c = 0; c < 64; c++) {
            const floatx4 vv = *(const floatx4*)&Vs[c * KV_STR + d0];
#pragma unroll
            for (int i = 0; i < 4; i++) acc[i] += Ps[(rg + 16 * i) * PS_STR + c] * vv;
        }
    }

    const int b = bh >> 5, h = bh & 31;
#pragma unroll
    for (int i = 0; i < 4; i++) {
        const int r = rg + 16 * i;
        const int t = qt * 64 + r;
        const float inv = 1.0f / l_s[r];
        const u16x4 ov = {f2b(acc[i].x * inv), f2b(acc[i].y * inv),
                          f2b(acc[i].z * inv), f2b(acc[i].w * inv)};
        *(u16x4*)(ctx + ((size_t)(b * T_ + t)) * C_ + h * HD_ + d0) = ov;
    }
}

extern "C" void kernel_launch(void* const* d_in, const int* in_sizes, int n_in,
                              void* d_out, int out_size, void* d_ws, size_t ws_size,
                              hipStream_t stream) {
    const float* x      = (const float*)d_in[0];
    // d_in[1] = mask (causal tril, implied), d_in[2] = index (arange, implied)
    const float* rope   = (const float*)d_in[3];
    const float* Wqkv_w = (const float*)d_in[4];
    const float* Wqkv_b = (const float*)d_in[5];
    const float* out_w  = (const float*)d_in[6];
    const float* out_b  = (const float*)d_in[7];
    // d_in[8]/d_in[9] = zero caches fully overwritten via index=arange -> ignored
    float* out = (float*)d_out;

    const size_t headElems = (size_t)B_ * H_ * T_ * HD_;  // 8388608
    u16* qTp = (u16*)d_ws;
    u16* kTp = qTp + headElems;
    u16* vTp = kTp + headElems;
    u16* ctx = vTp + headElems;  // ws use: 4 x 16 MiB = 64 MiB

    gemm_bt<0><<<dim3(48, 32), 256, 0, stream>>>(x, Wqkv_w, Wqkv_b, rope, qTp, kTp, vTp);
    attn_kernel<<<dim3(16, 128), 256, 0, stream>>>(qTp, kTp, vTp, ctx);
    gemm_bt<1><<<dim3(16, 32), 256, 0, stream>>>(ctx, out_w, out_b, rope, out, nullptr, nullptr);
}

// Round 3
// 584.382 us; speedup vs baseline: 2.2687x; 2.2687x over previous
//
#include <hip/hip_runtime.h>

typedef unsigned short u16;
typedef unsigned int u32;
typedef __bf16 bf16x8 __attribute__((ext_vector_type(8)));
typedef float floatx4 __attribute__((ext_vector_type(4)));
typedef u16 u16x4 __attribute__((ext_vector_type(4)));
typedef u16 u16x8 __attribute__((ext_vector_type(8)));

#define B_ 4
#define T_ 1024
#define C_ 2048
#define H_ 32
#define HD_ 64

__device__ __forceinline__ float b2f(u16 u) {
    u32 x = ((u32)u) << 16;
    return __builtin_bit_cast(float, x);
}
__device__ __forceinline__ u16 f2b(float f) {
    u32 i = __builtin_bit_cast(u32, f);
    u32 r = (i + 0x7FFFu + ((i >> 16) & 1u)) >> 16;   // round-nearest-even
    return (u16)r;
}

// ---------------------------------------------------------------------------
// GEMM: C[m,n] = sum_k A[m,k] * W[n,k] + bias[n]   (unchanged from round 2)
// ---------------------------------------------------------------------------
template <int MODE>
__global__ __launch_bounds__(256) void gemm_bt(const void* __restrict__ Av,
                                               const float* __restrict__ W,
                                               const float* __restrict__ bias,
                                               const float* __restrict__ rope,
                                               void* __restrict__ o0v,
                                               u16* __restrict__ o1,
                                               u16* __restrict__ o2) {
    const int Kdim = 2048;
    __shared__ __align__(16) u16 As[128 * 64];
    __shared__ __align__(16) u16 Bs[128 * 64];

    const int tid = threadIdx.x;
    const int w = tid >> 6, lane = tid & 63;
    const int wr = w >> 1, wc = w & 1;
    const int quad = lane >> 4, l15 = lane & 15;
    const int mBase = blockIdx.y * 128, nBase = blockIdx.x * 128;

    floatx4 acc[4][4] = {};

    for (int k0 = 0; k0 < Kdim; k0 += 64) {
        if (MODE == 0) {
            const float* Af = (const float*)Av;
#pragma unroll
            for (int p = 0; p < 8; p++) {
                const int idx = p * 1024 + tid * 4;
                const int row = idx >> 6, col = idx & 63;
                const floatx4 v = *(const floatx4*)(Af + (size_t)(mBase + row) * Kdim + k0 + col);
                const u16x4 h = {f2b(v.x), f2b(v.y), f2b(v.z), f2b(v.w)};
                *(u16x4*)&As[row * 64 + col] = h;
            }
        } else {
            const u16* Ab = (const u16*)Av;
#pragma unroll
            for (int p = 0; p < 4; p++) {
                const int idx = p * 2048 + tid * 8;
                const int row = idx >> 6, col = idx & 63;
                *(u16x8*)&As[row * 64 + col] =
                    *(const u16x8*)(Ab + (size_t)(mBase + row) * Kdim + k0 + col);
            }
        }
#pragma unroll
        for (int p = 0; p < 8; p++) {
            const int idx = p * 1024 + tid * 4;
            const int row = idx >> 6, col = idx & 63;
            const floatx4 v = *(const floatx4*)(W + (size_t)(nBase + row) * Kdim + k0 + col);
            const u16x4 h = {f2b(v.x), f2b(v.y), f2b(v.z), f2b(v.w)};
            *(u16x4*)&Bs[row * 64 + col] = h;
        }
        __syncthreads();

#pragma unroll
        for (int ks = 0; ks < 64; ks += 32) {
            bf16x8 af[4], bfr[4];
#pragma unroll
            for (int i = 0; i < 4; i++)
                af[i] = *(const bf16x8*)&As[(wr * 64 + i * 16 + l15) * 64 + ks + quad * 8];
#pragma unroll
            for (int j = 0; j < 4; j++)
                bfr[j] = *(const bf16x8*)&Bs[(wc * 64 + j * 16 + l15) * 64 + ks + quad * 8];
#pragma unroll
            for (int i = 0; i < 4; i++)
#pragma unroll
                for (int j = 0; j < 4; j++)
                    acc[i][j] = __builtin_amdgcn_mfma_f32_16x16x32_bf16(af[i], bfr[j], acc[i][j], 0, 0, 0);
        }
        __syncthreads();
    }

    const int nq = nBase + wc * 64;
    float bv[4];
#pragma unroll
    for (int j = 0; j < 4; j++) bv[j] = bias[nq + j * 16 + l15];

    if (MODE == 0) {
        const int region = nq >> 11;
        const int h = (nq & 2047) >> 6;
        const int d = l15;
        u16* dst = (region == 0) ? (u16*)o0v : ((region == 1) ? o1 : o2);
#pragma unroll
        for (int i = 0; i < 4; i++) {
#pragma unroll
            for (int r = 0; r < 4; r++) {
                const int m = mBase + wr * 64 + i * 16 + quad * 4 + r;
                const int b = m >> 10, t = m & 1023;
                float v0 = acc[i][0][r] + bv[0];
                float v1 = acc[i][1][r] + bv[1];
                float v2 = acc[i][2][r] + bv[2];
                float v3 = acc[i][3][r] + bv[3];
                const size_t base = ((size_t)(b * H_ + h) * T_ + t) * HD_;
                if (region < 2) {
                    const float cz = rope[t * 32 + d * 2];
                    const float sz = rope[t * 32 + d * 2 + 1];
                    const float n0 = v0 * cz - v1 * sz;
                    const float n1 = v1 * cz + v0 * sz;
                    dst[base + d] = f2b(n0);
                    dst[base + 16 + d] = f2b(n1);
                } else {
                    dst[base + d] = f2b(v0);
                    dst[base + 16 + d] = f2b(v1);
                }
                dst[base + 32 + d] = f2b(v2);
                dst[base + 48 + d] = f2b(v3);
            }
        }
    } else {
        float* outf = (float*)o0v;
#pragma unroll
        for (int i = 0; i < 4; i++)
#pragma unroll
            for (int r = 0; r < 4; r++) {
                const int m = mBase + wr * 64 + i * 16 + quad * 4 + r;
                const size_t o = (size_t)m * 2048 + nq;
#pragma unroll
                for (int j = 0; j < 4; j++)
                    outf[o + j * 16 + l15] = acc[i][j][r] + bv[j];
            }
    }
}

// ---------------------------------------------------------------------------
// MFMA flash attention. Block = (b,h) x 64-query tile, 4 waves x 16 q-rows.
// Computes S^T = K @ Q^T (so K and Q frags load straight from global, 16B
// contiguous), softmax over keys = in-lane (16 vals) + shfl_xor 16/32,
// P^T round-trips through wave-private LDS (no barrier), PV as O^T = V^T @ P
// with V^T staged block-wide in LDS (2 barriers/ktile, stride 72 => 2-way
// bank aliasing = free).
// Fragment maps (m89): A[m][k]: m=lane&15, k=quad*8+j. B[k][n]: n=lane&15,
// k=quad*8+j. C[row][col]: col=lane&15, row=quad*4+r.
// ---------------------------------------------------------------------------
#define VT_STR 72

__global__ __launch_bounds__(256) void attn_mfma(const u16* __restrict__ qT,
                                                 const u16* __restrict__ kT,
                                                 const u16* __restrict__ vT,
                                                 u16* __restrict__ ctx) {
    __shared__ __align__(16) u16 Vt[64 * VT_STR];        // V^T: [hd][key]
    __shared__ __align__(16) u16 Pt[4 * 16 * VT_STR];    // per-wave P^T: [q][key]

    const int tid = threadIdx.x;
    const int w = tid >> 6, lane = tid & 63;
    const int quad = lane >> 4, l15 = lane & 15;
    const int qt = 15 - (int)blockIdx.x;   // big tiles dispatch first
    const int bh = blockIdx.y;
    const size_t headBase = (size_t)bh * (T_ * HD_);

    // Q fragments: B-operand of S^T = contiguous row-major load of Q
    bf16x8 qf[2];
    {
        const u16* qrow = qT + headBase + ((size_t)qt * 64 + w * 16 + l15) * HD_ + quad * 8;
        qf[0] = __builtin_bit_cast(bf16x8, *(const u16x8*)(qrow));
        qf[1] = __builtin_bit_cast(bf16x8, *(const u16x8*)(qrow + 32));
    }

    u16* myPt = &Pt[w * 16 * VT_STR];
    const int vhd = tid & 63, vkb = tid >> 6;   // V^T staging role
    float m_i = -1e30f, l_i = 0.f;
    floatx4 oacc[4] = {};

    for (int kt = 0; kt <= qt; kt++) {
        const u16* kp = kT + headBase + (size_t)kt * 64 * HD_;
        const u16* vp = vT + headBase + (size_t)kt * 64 * HD_;

        // gather V^T staging values (coalesced: lane -> hd)
        u16 vreg[16];
#pragma unroll
        for (int c = 0; c < 16; c++)
            vreg[c] = vp[(vkb * 16 + c) * HD_ + vhd];

        // S^T = K @ Q^T : A=K frags direct from global
        floatx4 st[4] = {};
#pragma unroll
        for (int mi = 0; mi < 4; mi++) {
            const u16* krow = kp + (mi * 16 + l15) * HD_ + quad * 8;
            const bf16x8 kf0 = __builtin_bit_cast(bf16x8, *(const u16x8*)(krow));
            const bf16x8 kf1 = __builtin_bit_cast(bf16x8, *(const u16x8*)(krow + 32));
            st[mi] = __builtin_amdgcn_mfma_f32_16x16x32_bf16(kf0, qf[0], st[mi], 0, 0, 0);
            st[mi] = __builtin_amdgcn_mfma_f32_16x16x32_bf16(kf1, qf[1], st[mi], 0, 0, 0);
        }

        __syncthreads();   // all waves done reading Vt (prev PV)
#pragma unroll
        for (int c4 = 0; c4 < 4; c4++) {
            const u16x4 vv = {vreg[c4 * 4], vreg[c4 * 4 + 1], vreg[c4 * 4 + 2], vreg[c4 * 4 + 3]};
            *(u16x4*)&Vt[vhd * VT_STR + vkb * 16 + c4 * 4] = vv;
        }
        __syncthreads();   // Vt ready

        // softmax over keys (cols of S^T live in-lane + across quads)
        float pmax = -1e30f;
#pragma unroll
        for (int mi = 0; mi < 4; mi++)
#pragma unroll
            for (int r = 0; r < 4; r++) {
                float sv = st[mi][r] * 0.125f;   // 1/sqrt(64)
                if (kt == qt && (mi * 16 + quad * 4 + r) > (w * 16 + l15)) sv = -1e30f;
                st[mi][r] = sv;
                pmax = fmaxf(pmax, sv);
            }
        pmax = fmaxf(pmax, __shfl_xor(pmax, 16, 64));
        pmax = fmaxf(pmax, __shfl_xor(pmax, 32, 64));
        const float mnew = fmaxf(m_i, pmax);
        const float alpha = __expf(m_i - mnew);
        m_i = mnew;

        float psum = 0.f;
#pragma unroll
        for (int mi = 0; mi < 4; mi++) {
            u16x4 pk;
#pragma unroll
            for (int r = 0; r < 4; r++) {
                const float p = __expf(st[mi][r] - mnew);
                psum += p;
                pk[r] = f2b(p);
            }
            *(u16x4*)&myPt[l15 * VT_STR + mi * 16 + quad * 4] = pk;  // P^T[q][key]
        }
        psum += __shfl_xor(psum, 16, 64);
        psum += __shfl_xor(psum, 32, 64);
        l_i = l_i * alpha + psum;

#pragma unroll
        for (int mi = 0; mi < 4; mi++) oacc[mi] *= alpha;

        // O^T += V^T @ P : A=V^T frags (LDS), B=P frags (wave-private LDS)
        bf16x8 pf[2];
        pf[0] = __builtin_bit_cast(bf16x8, *(const u16x8*)&myPt[l15 * VT_STR + quad * 8]);
        pf[1] = __builtin_bit_cast(bf16x8, *(const u16x8*)&myPt[l15 * VT_STR + 32 + quad * 8]);
#pragma unroll
        for (int mi = 0; mi < 4; mi++) {
            const bf16x8 vf0 = __builtin_bit_cast(bf16x8, *(const u16x8*)&Vt[(mi * 16 + l15) * VT_STR + quad * 8]);
            const bf16x8 vf1 = __builtin_bit_cast(bf16x8, *(const u16x8*)&Vt[(mi * 16 + l15) * VT_STR + 32 + quad * 8]);
            oacc[mi] = __builtin_amdgcn_mfma_f32_16x16x32_bf16(vf0, pf[0], oacc[mi], 0, 0, 0);
            oacc[mi] = __builtin_amdgcn_mfma_f32_16x16x32_bf16(vf1, pf[1], oacc[mi], 0, 0, 0);
        }
    }

    // epilogue: O^T[hd=mi*16+quad*4+r][q=l15] -> ctx[b][t][h*64+hd]
    const float inv = 1.0f / l_i;
    const int b = bh >> 5, h = bh & 31;
    const int t = qt * 64 + w * 16 + l15;
    u16* cp = ctx + ((size_t)(b * T_ + t)) * C_ + h * HD_;
#pragma unroll
    for (int mi = 0; mi < 4; mi++) {
        const u16x4 ov = {f2b(oacc[mi][0] * inv), f2b(oacc[mi][1] * inv),
                          f2b(oacc[mi][2] * inv), f2b(oacc[mi][3] * inv)};
        *(u16x4*)(cp + mi * 16 + quad * 4) = ov;
    }
}

extern "C" void kernel_launch(void* const* d_in, const int* in_sizes, int n_in,
                              void* d_out, int out_size, void* d_ws, size_t ws_size,
                              hipStream_t stream) {
    const float* x      = (const float*)d_in[0];
    const float* rope   = (const float*)d_in[3];
    const float* Wqkv_w = (const float*)d_in[4];
    const float* Wqkv_b = (const float*)d_in[5];
    const float* out_w  = (const float*)d_in[6];
    const float* out_b  = (const float*)d_in[7];
    float* out = (float*)d_out;

    const size_t headElems = (size_t)B_ * H_ * T_ * HD_;  // 8388608
    u16* qTp = (u16*)d_ws;
    u16* kTp = qTp + headElems;
    u16* vTp = kTp + headElems;
    u16* ctx = vTp + headElems;  // ws use: 4 x 16 MiB = 64 MiB

    gemm_bt<0><<<dim3(48, 32), 256, 0, stream>>>(x, Wqkv_w, Wqkv_b, rope, qTp, kTp, vTp);
    attn_mfma<<<dim3(16, 128), 256, 0, stream>>>(qTp, kTp, vTp, ctx);
    gemm_bt<1><<<dim3(16, 32), 256, 0, stream>>>(ctx, out_w, out_b, rope, out, nullptr, nullptr);
}

// Round 4
// 561.526 us; speedup vs baseline: 2.3611x; 1.0407x over previous
//
#include <hip/hip_runtime.h>

typedef unsigned short u16;
typedef unsigned int u32;
typedef __bf16 bf16x8 __attribute__((ext_vector_type(8)));
typedef float floatx4 __attribute__((ext_vector_type(4)));
typedef u16 u16x4 __attribute__((ext_vector_type(4)));
typedef u16 u16x8 __attribute__((ext_vector_type(8)));
typedef u32 u32x2 __attribute__((ext_vector_type(2)));

#define B_ 4
#define T_ 1024
#define C_ 2048
#define H_ 32
#define HD_ 64

__device__ __forceinline__ float b2f(u16 u) {
    u32 x = ((u32)u) << 16;
    return __builtin_bit_cast(float, x);
}
__device__ __forceinline__ u16 f2b(float f) {          // RNE (epilogue only)
    u32 i = __builtin_bit_cast(u32, f);
    u32 r = (i + 0x7FFFu + ((i >> 16) & 1u)) >> 16;
    return (u16)r;
}
// pack two fp32 -> two bf16 (round-half-up), 2 adds + 1 v_perm_b32
__device__ __forceinline__ u32 pack2(float a, float b) {
    const u32 ua = __builtin_bit_cast(u32, a) + 0x8000u;
    const u32 ub = __builtin_bit_cast(u32, b) + 0x8000u;
    return __builtin_amdgcn_perm(ub, ua, 0x07060302u);  // [ub_hi : ua_hi]
}

// ---------------------------------------------------------------------------
// GEMM: C[m,n] = sum_k A[m,k] * W[n,k] + bias[n]
// 128x128 tile, BK=64, 4 waves x (4x4) mfma_f32_16x16x32_bf16.
// LDS row stride 72 u16 (144 B): kills the 16-way bank conflicts of the
// 128 B stride (row->row bank shift 4 -> 2-way = free).
// Staging converts fp32->bf16 via pack2 (1 add/elem + 1 perm/pair).
// ---------------------------------------------------------------------------
#define AS_STR 72

template <int MODE>
__global__ __launch_bounds__(256) void gemm_bt(const void* __restrict__ Av,
                                               const float* __restrict__ W,
                                               const float* __restrict__ bias,
                                               const float* __restrict__ rope,
                                               void* __restrict__ o0v,
                                               u16* __restrict__ o1,
                                               u16* __restrict__ o2) {
    const int Kdim = 2048;
    __shared__ __align__(16) u16 As[128 * AS_STR];
    __shared__ __align__(16) u16 Bs[128 * AS_STR];

    const int tid = threadIdx.x;
    const int w = tid >> 6, lane = tid & 63;
    const int wr = w >> 1, wc = w & 1;
    const int quad = lane >> 4, l15 = lane & 15;
    const int mBase = blockIdx.y * 128, nBase = blockIdx.x * 128;

    floatx4 acc[4][4] = {};

    for (int k0 = 0; k0 < Kdim; k0 += 64) {
        if (MODE == 0) {
            const float* Af = (const float*)Av;
#pragma unroll
            for (int p = 0; p < 8; p++) {
                const int idx = p * 1024 + tid * 4;
                const int row = idx >> 6, col = idx & 63;
                const floatx4 v = *(const floatx4*)(Af + (size_t)(mBase + row) * Kdim + k0 + col);
                const u32x2 h = {pack2(v.x, v.y), pack2(v.z, v.w)};
                *(u32x2*)&As[row * AS_STR + col] = h;
            }
        } else {
            const u16* Ab = (const u16*)Av;
#pragma unroll
            for (int p = 0; p < 4; p++) {
                const int idx = p * 2048 + tid * 8;
                const int row = idx >> 6, col = idx & 63;
                *(u16x8*)&As[row * AS_STR + col] =
                    *(const u16x8*)(Ab + (size_t)(mBase + row) * Kdim + k0 + col);
            }
        }
#pragma unroll
        for (int p = 0; p < 8; p++) {
            const int idx = p * 1024 + tid * 4;
            const int row = idx >> 6, col = idx & 63;
            const floatx4 v = *(const floatx4*)(W + (size_t)(nBase + row) * Kdim + k0 + col);
            const u32x2 h = {pack2(v.x, v.y), pack2(v.z, v.w)};
            *(u32x2*)&Bs[row * AS_STR + col] = h;
        }
        __syncthreads();

#pragma unroll
        for (int ks = 0; ks < 64; ks += 32) {
            bf16x8 af[4], bfr[4];
#pragma unroll
            for (int i = 0; i < 4; i++)
                af[i] = *(const bf16x8*)&As[(wr * 64 + i * 16 + l15) * AS_STR + ks + quad * 8];
#pragma unroll
            for (int j = 0; j < 4; j++)
                bfr[j] = *(const bf16x8*)&Bs[(wc * 64 + j * 16 + l15) * AS_STR + ks + quad * 8];
#pragma unroll
            for (int i = 0; i < 4; i++)
#pragma unroll
                for (int j = 0; j < 4; j++)
                    acc[i][j] = __builtin_amdgcn_mfma_f32_16x16x32_bf16(af[i], bfr[j], acc[i][j], 0, 0, 0);
        }
        __syncthreads();
    }

    const int nq = nBase + wc * 64;
    float bv[4];
#pragma unroll
    for (int j = 0; j < 4; j++) bv[j] = bias[nq + j * 16 + l15];

    if (MODE == 0) {
        const int region = nq >> 11;            // 0=q 1=k 2=v (tile never straddles)
        const int h = (nq & 2047) >> 6;
        const int d = l15;
        u16* dst = (region == 0) ? (u16*)o0v : ((region == 1) ? o1 : o2);
#pragma unroll
        for (int i = 0; i < 4; i++) {
#pragma unroll
            for (int r = 0; r < 4; r++) {
                const int m = mBase + wr * 64 + i * 16 + quad * 4 + r;
                const int b = m >> 10, t = m & 1023;
                float v0 = acc[i][0][r] + bv[0];
                float v1 = acc[i][1][r] + bv[1];
                float v2 = acc[i][2][r] + bv[2];
                float v3 = acc[i][3][r] + bv[3];
                const size_t base = ((size_t)(b * H_ + h) * T_ + t) * HD_;
                if (region < 2) {
                    const float cz = rope[t * 32 + d * 2];
                    const float sz = rope[t * 32 + d * 2 + 1];
                    const float n0 = v0 * cz - v1 * sz;
                    const float n1 = v1 * cz + v0 * sz;
                    dst[base + d] = f2b(n0);
                    dst[base + 16 + d] = f2b(n1);
                } else {
                    dst[base + d] = f2b(v0);
                    dst[base + 16 + d] = f2b(v1);
                }
                dst[base + 32 + d] = f2b(v2);
                dst[base + 48 + d] = f2b(v3);
            }
        }
    } else {
        float* outf = (float*)o0v;
#pragma unroll
        for (int i = 0; i < 4; i++)
#pragma unroll
            for (int r = 0; r < 4; r++) {
                const int m = mBase + wr * 64 + i * 16 + quad * 4 + r;
                const size_t o = (size_t)m * 2048 + nq;
#pragma unroll
                for (int j = 0; j < 4; j++)
                    outf[o + j * 16 + l15] = acc[i][j][r] + bv[j];
            }
    }
}

// ---------------------------------------------------------------------------
// MFMA flash attention (unchanged from round 3).
// ---------------------------------------------------------------------------
#define VT_STR 72

__global__ __launch_bounds__(256) void attn_mfma(const u16* __restrict__ qT,
                                                 const u16* __restrict__ kT,
                                                 const u16* __restrict__ vT,
                                                 u16* __restrict__ ctx) {
    __shared__ __align__(16) u16 Vt[64 * VT_STR];        // V^T: [hd][key]
    __shared__ __align__(16) u16 Pt[4 * 16 * VT_STR];    // per-wave P^T: [q][key]

    const int tid = threadIdx.x;
    const int w = tid >> 6, lane = tid & 63;
    const int quad = lane >> 4, l15 = lane & 15;
    const int qt = 15 - (int)blockIdx.x;   // big tiles dispatch first
    const int bh = blockIdx.y;
    const size_t headBase = (size_t)bh * (T_ * HD_);

    bf16x8 qf[2];
    {
        const u16* qrow = qT + headBase + ((size_t)qt * 64 + w * 16 + l15) * HD_ + quad * 8;
        qf[0] = __builtin_bit_cast(bf16x8, *(const u16x8*)(qrow));
        qf[1] = __builtin_bit_cast(bf16x8, *(const u16x8*)(qrow + 32));
    }

    u16* myPt = &Pt[w * 16 * VT_STR];
    const int vhd = tid & 63, vkb = tid >> 6;
    float m_i = -1e30f, l_i = 0.f;
    floatx4 oacc[4] = {};

    for (int kt = 0; kt <= qt; kt++) {
        const u16* kp = kT + headBase + (size_t)kt * 64 * HD_;
        const u16* vp = vT + headBase + (size_t)kt * 64 * HD_;

        u16 vreg[16];
#pragma unroll
        for (int c = 0; c < 16; c++)
            vreg[c] = vp[(vkb * 16 + c) * HD_ + vhd];

        floatx4 st[4] = {};
#pragma unroll
        for (int mi = 0; mi < 4; mi++) {
            const u16* krow = kp + (mi * 16 + l15) * HD_ + quad * 8;
            const bf16x8 kf0 = __builtin_bit_cast(bf16x8, *(const u16x8*)(krow));
            const bf16x8 kf1 = __builtin_bit_cast(bf16x8, *(const u16x8*)(krow + 32));
            st[mi] = __builtin_amdgcn_mfma_f32_16x16x32_bf16(kf0, qf[0], st[mi], 0, 0, 0);
            st[mi] = __builtin_amdgcn_mfma_f32_16x16x32_bf16(kf1, qf[1], st[mi], 0, 0, 0);
        }

        __syncthreads();
#pragma unroll
        for (int c4 = 0; c4 < 4; c4++) {
            const u16x4 vv = {vreg[c4 * 4], vreg[c4 * 4 + 1], vreg[c4 * 4 + 2], vreg[c4 * 4 + 3]};
            *(u16x4*)&Vt[vhd * VT_STR + vkb * 16 + c4 * 4] = vv;
        }
        __syncthreads();

        float pmax = -1e30f;
#pragma unroll
        for (int mi = 0; mi < 4; mi++)
#pragma unroll
            for (int r = 0; r < 4; r++) {
                float sv = st[mi][r] * 0.125f;
                if (kt == qt && (mi * 16 + quad * 4 + r) > (w * 16 + l15)) sv = -1e30f;
                st[mi][r] = sv;
                pmax = fmaxf(pmax, sv);
            }
        pmax = fmaxf(pmax, __shfl_xor(pmax, 16, 64));
        pmax = fmaxf(pmax, __shfl_xor(pmax, 32, 64));
        const float mnew = fmaxf(m_i, pmax);
        const float alpha = __expf(m_i - mnew);
        m_i = mnew;

        float psum = 0.f;
#pragma unroll
        for (int mi = 0; mi < 4; mi++) {
            u16x4 pk;
#pragma unroll
            for (int r = 0; r < 4; r++) {
                const float p = __expf(st[mi][r] - mnew);
                psum += p;
                pk[r] = f2b(p);
            }
            *(u16x4*)&myPt[l15 * VT_STR + mi * 16 + quad * 4] = pk;
        }
        psum += __shfl_xor(psum, 16, 64);
        psum += __shfl_xor(psum, 32, 64);
        l_i = l_i * alpha + psum;

#pragma unroll
        for (int mi = 0; mi < 4; mi++) oacc[mi] *= alpha;

        bf16x8 pf[2];
        pf[0] = __builtin_bit_cast(bf16x8, *(const u16x8*)&myPt[l15 * VT_STR + quad * 8]);
        pf[1] = __builtin_bit_cast(bf16x8, *(const u16x8*)&myPt[l15 * VT_STR + 32 + quad * 8]);
#pragma unroll
        for (int mi = 0; mi < 4; mi++) {
            const bf16x8 vf0 = __builtin_bit_cast(bf16x8, *(const u16x8*)&Vt[(mi * 16 + l15) * VT_STR + quad * 8]);
            const bf16x8 vf1 = __builtin_bit_cast(bf16x8, *(const u16x8*)&Vt[(mi * 16 + l15) * VT_STR + 32 + quad * 8]);
            oacc[mi] = __builtin_amdgcn_mfma_f32_16x16x32_bf16(vf0, pf[0], oacc[mi], 0, 0, 0);
            oacc[mi] = __builtin_amdgcn_mfma_f32_16x16x32_bf16(vf1, pf[1], oacc[mi], 0, 0, 0);
        }
    }

    const float inv = 1.0f / l_i;
    const int b = bh >> 5, h = bh & 31;
    const int t = qt * 64 + w * 16 + l15;
    u16* cp = ctx + ((size_t)(b * T_ + t)) * C_ + h * HD_;
#pragma unroll
    for (int mi = 0; mi < 4; mi++) {
        const u16x4 ov = {f2b(oacc[mi][0] * inv), f2b(oacc[mi][1] * inv),
                          f2b(oacc[mi][2] * inv), f2b(oacc[mi][3] * inv)};
        *(u16x4*)(cp + mi * 16 + quad * 4) = ov;
    }
}

extern "C" void kernel_launch(void* const* d_in, const int* in_sizes, int n_in,
                              void* d_out, int out_size, void* d_ws, size_t ws_size,
                              hipStream_t stream) {
    const float* x      = (const float*)d_in[0];
    const float* rope   = (const float*)d_in[3];
    const float* Wqkv_w = (const float*)d_in[4];
    const float* Wqkv_b = (const float*)d_in[5];
    const float* out_w  = (const float*)d_in[6];
    const float* out_b  = (const float*)d_in[7];
    float* out = (float*)d_out;

    const size_t headElems = (size_t)B_ * H_ * T_ * HD_;  // 8388608
    u16* qTp = (u16*)d_ws;
    u16* kTp = qTp + headElems;
    u16* vTp = kTp + headElems;
    u16* ctx = vTp + headElems;  // ws use: 4 x 16 MiB = 64 MiB

    gemm_bt<0><<<dim3(48, 32), 256, 0, stream>>>(x, Wqkv_w, Wqkv_b, rope, qTp, kTp, vTp);
    attn_mfma<<<dim3(16, 128), 256, 0, stream>>>(qTp, kTp, vTp, ctx);
    gemm_bt<1><<<dim3(16, 32), 256, 0, stream>>>(ctx, out_w, out_b, rope, out, nullptr, nullptr);
}

// Round 5
// 513.343 us; speedup vs baseline: 2.5827x; 1.0939x over previous
//
#include <hip/hip_runtime.h>

typedef unsigned short u16;
typedef unsigned int u32;
typedef __bf16 bf16x8 __attribute__((ext_vector_type(8)));
typedef float floatx4 __attribute__((ext_vector_type(4)));
typedef u16 u16x4 __attribute__((ext_vector_type(4)));
typedef u16 u16x8 __attribute__((ext_vector_type(8)));
typedef u32 u32x2 __attribute__((ext_vector_type(2)));

#define B_ 4
#define T_ 1024
#define C_ 2048
#define H_ 32
#define HD_ 64

__device__ __forceinline__ float b2f(u16 u) {
    u32 x = ((u32)u) << 16;
    return __builtin_bit_cast(float, x);
}
__device__ __forceinline__ u16 f2b(float f) {          // RNE (epilogues)
    u32 i = __builtin_bit_cast(u32, f);
    u32 r = (i + 0x7FFFu + ((i >> 16) & 1u)) >> 16;
    return (u16)r;
}
// pack two fp32 -> two bf16 (round-half-up), 2 adds + 1 v_perm_b32
__device__ __forceinline__ u32 pack2(float a, float b) {
    const u32 ua = __builtin_bit_cast(u32, a) + 0x8000u;
    const u32 ub = __builtin_bit_cast(u32, b) + 0x8000u;
    return __builtin_amdgcn_perm(ub, ua, 0x07060302u);  // [ub_hi : ua_hi]
}

#define GLOAD16(gp, lp) __builtin_amdgcn_global_load_lds( \
    (const __attribute__((address_space(1))) void*)(gp),  \
    (__attribute__((address_space(3))) void*)(lp), 16, 0, 0)

// ---------------------------------------------------------------------------
// fp32 -> bf16 elementwise convert (HBM-bound prework, ~30 us total)
// ---------------------------------------------------------------------------
__global__ __launch_bounds__(256) void convert_bf16(const float* __restrict__ src,
                                                    u16* __restrict__ dst, int n4) {
    const int stride = gridDim.x * 256;
    for (int i = blockIdx.x * 256 + threadIdx.x; i < n4; i += stride) {
        const floatx4 v = *(const floatx4*)(src + (size_t)i * 4);
        const u32x2 h = {pack2(v.x, v.y), pack2(v.z, v.w)};
        *(u32x2*)(dst + (size_t)i * 4) = h;
    }
}

// ---------------------------------------------------------------------------
// GEMM: C[m,n] = sum_k A[m,k] * W[n,k] + bias[n]   (A, W bf16 row-major)
// m97 structure: 128x128 tile, BK=64, global_load_lds width=16 staging
// (16 chunks of 8rows x 64cols, wave w takes chunks i*4+w; lane i lands at
// elems [8i,8i+8) = row-major), 4 waves x (4x4) mfma_f32_16x16x32_bf16.
// MODE 0: epilogue bias + RoPE + scatter to q/k/v (B,H,T,hd) bf16.
// MODE 1: epilogue bias, fp32 row-major store.
// ---------------------------------------------------------------------------
template <int MODE>
__global__ __launch_bounds__(256) void gemm_bt(const u16* __restrict__ A,
                                               const u16* __restrict__ W,
                                               const float* __restrict__ bias,
                                               const float* __restrict__ rope,
                                               void* __restrict__ o0v,
                                               u16* __restrict__ o1,
                                               u16* __restrict__ o2) {
    const int Kdim = 2048;
    __shared__ __align__(16) u16 As[128 * 64];
    __shared__ __align__(16) u16 Bs[128 * 64];

    const int tid = threadIdx.x;
    const int w = tid >> 6, lane = tid & 63;
    const int wr = w >> 1, wc = w & 1;
    const int quad = lane >> 4, l15 = lane & 15;
    const int mBase = blockIdx.y * 128, nBase = blockIdx.x * 128;

    floatx4 acc[4][4] = {};

    const int lrow = lane >> 3, lcol = (lane & 7) * 8;
    const u16* Ap = A + (size_t)(mBase + lrow) * Kdim + lcol;
    const u16* Wp = W + (size_t)(nBase + lrow) * Kdim + lcol;

    for (int k0 = 0; k0 < Kdim; k0 += 64) {
#pragma unroll
        for (int i = 0; i < 4; i++) {
            const int c = i * 4 + w;
            GLOAD16(Ap + (size_t)c * 8 * Kdim + k0, &As[c * 512]);
            GLOAD16(Wp + (size_t)c * 8 * Kdim + k0, &Bs[c * 512]);
        }
        __syncthreads();
#pragma unroll
        for (int ks = 0; ks < 64; ks += 32) {
            bf16x8 af[4], bfr[4];
#pragma unroll
            for (int i = 0; i < 4; i++)
                af[i] = *(const bf16x8*)&As[(wr * 64 + i * 16 + l15) * 64 + ks + quad * 8];
#pragma unroll
            for (int j = 0; j < 4; j++)
                bfr[j] = *(const bf16x8*)&Bs[(wc * 64 + j * 16 + l15) * 64 + ks + quad * 8];
#pragma unroll
            for (int i = 0; i < 4; i++)
#pragma unroll
                for (int j = 0; j < 4; j++)
                    acc[i][j] = __builtin_amdgcn_mfma_f32_16x16x32_bf16(af[i], bfr[j], acc[i][j], 0, 0, 0);
        }
        __syncthreads();
    }

    // epilogue: C/D layout col = lane&15 (per j-frag), row = quad*4 + reg (per i-frag)
    const int nq = nBase + wc * 64;
    float bv[4];
#pragma unroll
    for (int j = 0; j < 4; j++) bv[j] = bias[nq + j * 16 + l15];

    if (MODE == 0) {
        const int region = nq >> 11;            // 0=q 1=k 2=v (tile never straddles)
        const int h = (nq & 2047) >> 6;
        const int d = l15;
        u16* dst = (region == 0) ? (u16*)o0v : ((region == 1) ? o1 : o2);
#pragma unroll
        for (int i = 0; i < 4; i++) {
#pragma unroll
            for (int r = 0; r < 4; r++) {
                const int m = mBase + wr * 64 + i * 16 + quad * 4 + r;
                const int b = m >> 10, t = m & 1023;
                float v0 = acc[i][0][r] + bv[0];
                float v1 = acc[i][1][r] + bv[1];
                float v2 = acc[i][2][r] + bv[2];
                float v3 = acc[i][3][r] + bv[3];
                const size_t base = ((size_t)(b * H_ + h) * T_ + t) * HD_;
                if (region < 2) {
                    const float cz = rope[t * 32 + d * 2];
                    const float sz = rope[t * 32 + d * 2 + 1];
                    const float n0 = v0 * cz - v1 * sz;
                    const float n1 = v1 * cz + v0 * sz;
                    dst[base + d] = f2b(n0);
                    dst[base + 16 + d] = f2b(n1);
                } else {
                    dst[base + d] = f2b(v0);
                    dst[base + 16 + d] = f2b(v1);
                }
                dst[base + 32 + d] = f2b(v2);
                dst[base + 48 + d] = f2b(v3);
            }
        }
    } else {
        float* outf = (float*)o0v;
#pragma unroll
        for (int i = 0; i < 4; i++)
#pragma unroll
            for (int r = 0; r < 4; r++) {
                const int m = mBase + wr * 64 + i * 16 + quad * 4 + r;
                const size_t o = (size_t)m * 2048 + nq;
#pragma unroll
                for (int j = 0; j < 4; j++)
                    outf[o + j * 16 + l15] = acc[i][j][r] + bv[j];
            }
    }
}

// ---------------------------------------------------------------------------
// MFMA flash attention (unchanged — verified rounds 3/4).
// ---------------------------------------------------------------------------
#define VT_STR 72

__global__ __launch_bounds__(256) void attn_mfma(const u16* __restrict__ qT,
                                                 const u16* __restrict__ kT,
                                                 const u16* __restrict__ vT,
                                                 u16* __restrict__ ctx) {
    __shared__ __align__(16) u16 Vt[64 * VT_STR];        // V^T: [hd][key]
    __shared__ __align__(16) u16 Pt[4 * 16 * VT_STR];    // per-wave P^T: [q][key]

    const int tid = threadIdx.x;
    const int w = tid >> 6, lane = tid & 63;
    const int quad = lane >> 4, l15 = lane & 15;
    const int qt = 15 - (int)blockIdx.x;   // big tiles dispatch first
    const int bh = blockIdx.y;
    const size_t headBase = (size_t)bh * (T_ * HD_);

    bf16x8 qf[2];
    {
        const u16* qrow = qT + headBase + ((size_t)qt * 64 + w * 16 + l15) * HD_ + quad * 8;
        qf[0] = __builtin_bit_cast(bf16x8, *(const u16x8*)(qrow));
        qf[1] = __builtin_bit_cast(bf16x8, *(const u16x8*)(qrow + 32));
    }

    u16* myPt = &Pt[w * 16 * VT_STR];
    const int vhd = tid & 63, vkb = tid >> 6;
    float m_i = -1e30f, l_i = 0.f;
    floatx4 oacc[4] = {};

    for (int kt = 0; kt <= qt; kt++) {
        const u16* kp = kT + headBase + (size_t)kt * 64 * HD_;
        const u16* vp = vT + headBase + (size_t)kt * 64 * HD_;

        u16 vreg[16];
#pragma unroll
        for (int c = 0; c < 16; c++)
            vreg[c] = vp[(vkb * 16 + c) * HD_ + vhd];

        floatx4 st[4] = {};
#pragma unroll
        for (int mi = 0; mi < 4; mi++) {
            const u16* krow = kp + (mi * 16 + l15) * HD_ + quad * 8;
            const bf16x8 kf0 = __builtin_bit_cast(bf16x8, *(const u16x8*)(krow));
            const bf16x8 kf1 = __builtin_bit_cast(bf16x8, *(const u16x8*)(krow + 32));
            st[mi] = __builtin_amdgcn_mfma_f32_16x16x32_bf16(kf0, qf[0], st[mi], 0, 0, 0);
            st[mi] = __builtin_amdgcn_mfma_f32_16x16x32_bf16(kf1, qf[1], st[mi], 0, 0, 0);
        }

        __syncthreads();
#pragma unroll
        for (int c4 = 0; c4 < 4; c4++) {
            const u16x4 vv = {vreg[c4 * 4], vreg[c4 * 4 + 1], vreg[c4 * 4 + 2], vreg[c4 * 4 + 3]};
            *(u16x4*)&Vt[vhd * VT_STR + vkb * 16 + c4 * 4] = vv;
        }
        __syncthreads();

        float pmax = -1e30f;
#pragma unroll
        for (int mi = 0; mi < 4; mi++)
#pragma unroll
            for (int r = 0; r < 4; r++) {
                float sv = st[mi][r] * 0.125f;
                if (kt == qt && (mi * 16 + quad * 4 + r) > (w * 16 + l15)) sv = -1e30f;
                st[mi][r] = sv;
                pmax = fmaxf(pmax, sv);
            }
        pmax = fmaxf(pmax, __shfl_xor(pmax, 16, 64));
        pmax = fmaxf(pmax, __shfl_xor(pmax, 32, 64));
        const float mnew = fmaxf(m_i, pmax);
        const float alpha = __expf(m_i - mnew);
        m_i = mnew;

        float psum = 0.f;
#pragma unroll
        for (int mi = 0; mi < 4; mi++) {
            u16x4 pk;
#pragma unroll
            for (int r = 0; r < 4; r++) {
                const float p = __expf(st[mi][r] - mnew);
                psum += p;
                pk[r] = f2b(p);
            }
            *(u16x4*)&myPt[l15 * VT_STR + mi * 16 + quad * 4] = pk;
        }
        psum += __shfl_xor(psum, 16, 64);
        psum += __shfl_xor(psum, 32, 64);
        l_i = l_i * alpha + psum;

#pragma unroll
        for (int mi = 0; mi < 4; mi++) oacc[mi] *= alpha;

        bf16x8 pf[2];
        pf[0] = __builtin_bit_cast(bf16x8, *(const u16x8*)&myPt[l15 * VT_STR + quad * 8]);
        pf[1] = __builtin_bit_cast(bf16x8, *(const u16x8*)&myPt[l15 * VT_STR + 32 + quad * 8]);
#pragma unroll
        for (int mi = 0; mi < 4; mi++) {
            const bf16x8 vf0 = __builtin_bit_cast(bf16x8, *(const u16x8*)&Vt[(mi * 16 + l15) * VT_STR + quad * 8]);
            const bf16x8 vf1 = __builtin_bit_cast(bf16x8, *(const u16x8*)&Vt[(mi * 16 + l15) * VT_STR + 32 + quad * 8]);
            oacc[mi] = __builtin_amdgcn_mfma_f32_16x16x32_bf16(vf0, pf[0], oacc[mi], 0, 0, 0);
            oacc[mi] = __builtin_amdgcn_mfma_f32_16x16x32_bf16(vf1, pf[1], oacc[mi], 0, 0, 0);
        }
    }

    const float inv = 1.0f / l_i;
    const int b = bh >> 5, h = bh & 31;
    const int t = qt * 64 + w * 16 + l15;
    u16* cp = ctx + ((size_t)(b * T_ + t)) * C_ + h * HD_;
#pragma unroll
    for (int mi = 0; mi < 4; mi++) {
        const u16x4 ov = {f2b(oacc[mi][0] * inv), f2b(oacc[mi][1] * inv),
                          f2b(oacc[mi][2] * inv), f2b(oacc[mi][3] * inv)};
        *(u16x4*)(cp + mi * 16 + quad * 4) = ov;
    }
}

extern "C" void kernel_launch(void* const* d_in, const int* in_sizes, int n_in,
                              void* d_out, int out_size, void* d_ws, size_t ws_size,
                              hipStream_t stream) {
    const float* x      = (const float*)d_in[0];
    const float* rope   = (const float*)d_in[3];
    const float* Wqkv_w = (const float*)d_in[4];
    const float* Wqkv_b = (const float*)d_in[5];
    const float* out_w  = (const float*)d_in[6];
    const float* out_b  = (const float*)d_in[7];
    float* out = (float*)d_out;

    // ws layout (u16 elems), total 100.7 MB:
    //   xb 8.39M | wqkvb 12.58M | outwb 4.19M | qT 8.39M | kT 8.39M | vT 8.39M
    //   ctx aliases xb (x dead after gemm0)
    const size_t headElems = (size_t)B_ * H_ * T_ * HD_;     // 8388608
    u16* xb    = (u16*)d_ws;
    u16* wqkvb = xb + headElems;
    u16* outwb = wqkvb + 12582912;
    u16* qTp   = outwb + 4194304;
    u16* kTp   = qTp + headElems;
    u16* vTp   = kTp + headElems;
    u16* ctx   = xb;

    convert_bf16<<<dim3(2048), 256, 0, stream>>>(x, xb, 2097152);
    convert_bf16<<<dim3(3072), 256, 0, stream>>>(Wqkv_w, wqkvb, 3145728);
    convert_bf16<<<dim3(1024), 256, 0, stream>>>(out_w, outwb, 1048576);

    gemm_bt<0><<<dim3(48, 32), 256, 0, stream>>>(xb, wqkvb, Wqkv_b, rope, qTp, kTp, vTp);
    attn_mfma<<<dim3(16, 128), 256, 0, stream>>>(qTp, kTp, vTp, ctx);
    gemm_bt<1><<<dim3(16, 32), 256, 0, stream>>>(ctx, outwb, out_b, rope, out, nullptr, nullptr);
}

// Round 6
// 477.350 us; speedup vs baseline: 2.7774x; 1.0754x over previous
//
#include <hip/hip_runtime.h>

typedef unsigned short u16;
typedef unsigned int u32;
typedef __bf16 bf16x8 __attribute__((ext_vector_type(8)));
typedef float floatx4 __attribute__((ext_vector_type(4)));
typedef u16 u16x4 __attribute__((ext_vector_type(4)));
typedef u16 u16x8 __attribute__((ext_vector_type(8)));
typedef u32 u32x2 __attribute__((ext_vector_type(2)));

#define B_ 4
#define T_ 1024
#define C_ 2048
#define H_ 32
#define HD_ 64

__device__ __forceinline__ float b2f(u16 u) {
    u32 x = ((u32)u) << 16;
    return __builtin_bit_cast(float, x);
}
__device__ __forceinline__ u16 f2b(float f) {          // RNE (epilogues)
    u32 i = __builtin_bit_cast(u32, f);
    u32 r = (i + 0x7FFFu + ((i >> 16) & 1u)) >> 16;
    return (u16)r;
}
// pack two fp32 -> two bf16 (round-half-up), 2 adds + 1 v_perm_b32
__device__ __forceinline__ u32 pack2(float a, float b) {
    const u32 ua = __builtin_bit_cast(u32, a) + 0x8000u;
    const u32 ub = __builtin_bit_cast(u32, b) + 0x8000u;
    return __builtin_amdgcn_perm(ub, ua, 0x07060302u);  // [ub_hi : ua_hi]
}

#define GLOAD16(gp, lp) __builtin_amdgcn_global_load_lds( \
    (const __attribute__((address_space(1))) void*)(gp),  \
    (__attribute__((address_space(3))) void*)(lp), 16, 0, 0)

// ---------------------------------------------------------------------------
// fp32 -> bf16 elementwise convert (HBM-bound prework)
// ---------------------------------------------------------------------------
__global__ __launch_bounds__(256) void convert_bf16(const float* __restrict__ src,
                                                    u16* __restrict__ dst, int n4) {
    const int stride = gridDim.x * 256;
    for (int i = blockIdx.x * 256 + threadIdx.x; i < n4; i += stride) {
        const floatx4 v = *(const floatx4*)(src + (size_t)i * 4);
        const u32x2 h = {pack2(v.x, v.y), pack2(v.z, v.w)};
        *(u32x2*)(dst + (size_t)i * 4) = h;
    }
}

// ---------------------------------------------------------------------------
// GEMM: C[m,n] = sum_k A[m,k] * W[n,k] + bias[n]   (A, W bf16 row-major)
// m97 structure + XOR-swizzled LDS: staging lane (row r=lane>>3, slot s=lane&7)
// fetches global col-block s^r, so LDS slot (r,s) holds block s^r. Fragment
// read of row R, col-block cb -> slot cb^(R&7). Quad's 16 lanes then spread
// over all 32 banks (2-way = free) instead of 16-way conflicting.
// MODE 0: epilogue bias + RoPE + scatter to q/k/v (B,H,T,hd) bf16.
// MODE 1: epilogue bias, fp32 row-major store.
// ---------------------------------------------------------------------------
template <int MODE>
__global__ __launch_bounds__(256) void gemm_bt(const u16* __restrict__ A,
                                               const u16* __restrict__ W,
                                               const float* __restrict__ bias,
                                               const float* __restrict__ rope,
                                               void* __restrict__ o0v,
                                               u16* __restrict__ o1,
                                               u16* __restrict__ o2) {
    const int Kdim = 2048;
    __shared__ __align__(16) u16 As[128 * 64];
    __shared__ __align__(16) u16 Bs[128 * 64];

    const int tid = threadIdx.x;
    const int w = tid >> 6, lane = tid & 63;
    const int wr = w >> 1, wc = w & 1;
    const int quad = lane >> 4, l15 = lane & 15;
    const int mBase = blockIdx.y * 128, nBase = blockIdx.x * 128;

    floatx4 acc[4][4] = {};

    // swizzled staging: local row lrow, fetch col-block (lane&7)^lrow
    const int lrow = lane >> 3;
    const int lcol = ((lane & 7) ^ lrow) * 8;
    const u16* Ap = A + (size_t)(mBase + lrow) * Kdim + lcol;
    const u16* Wp = W + (size_t)(nBase + lrow) * Kdim + lcol;

    const int xk = l15 & 7;   // read-side XOR key (row & 7)

    for (int k0 = 0; k0 < Kdim; k0 += 64) {
#pragma unroll
        for (int i = 0; i < 4; i++) {
            const int c = i * 4 + w;
            GLOAD16(Ap + (size_t)c * 8 * Kdim + k0, &As[c * 512]);
            GLOAD16(Wp + (size_t)c * 8 * Kdim + k0, &Bs[c * 512]);
        }
        __syncthreads();
#pragma unroll
        for (int ks = 0; ks < 64; ks += 32) {
            bf16x8 af[4], bfr[4];
#pragma unroll
            for (int i = 0; i < 4; i++) {
                const int co = (((ks >> 3) + quad) ^ xk) * 8;
                af[i] = *(const bf16x8*)&As[(wr * 64 + i * 16 + l15) * 64 + co];
            }
#pragma unroll
            for (int j = 0; j < 4; j++) {
                const int co = (((ks >> 3) + quad) ^ xk) * 8;
                bfr[j] = *(const bf16x8*)&Bs[(wc * 64 + j * 16 + l15) * 64 + co];
            }
#pragma unroll
            for (int i = 0; i < 4; i++)
#pragma unroll
                for (int j = 0; j < 4; j++)
                    acc[i][j] = __builtin_amdgcn_mfma_f32_16x16x32_bf16(af[i], bfr[j], acc[i][j], 0, 0, 0);
        }
        __syncthreads();
    }

    // epilogue: C/D layout col = lane&15 (per j-frag), row = quad*4 + reg (per i-frag)
    const int nq = nBase + wc * 64;
    float bv[4];
#pragma unroll
    for (int j = 0; j < 4; j++) bv[j] = bias[nq + j * 16 + l15];

    if (MODE == 0) {
        const int region = nq >> 11;            // 0=q 1=k 2=v (tile never straddles)
        const int h = (nq & 2047) >> 6;
        const int d = l15;
        u16* dst = (region == 0) ? (u16*)o0v : ((region == 1) ? o1 : o2);
#pragma unroll
        for (int i = 0; i < 4; i++) {
#pragma unroll
            for (int r = 0; r < 4; r++) {
                const int m = mBase + wr * 64 + i * 16 + quad * 4 + r;
                const int b = m >> 10, t = m & 1023;
                float v0 = acc[i][0][r] + bv[0];
                float v1 = acc[i][1][r] + bv[1];
                float v2 = acc[i][2][r] + bv[2];
                float v3 = acc[i][3][r] + bv[3];
                const size_t base = ((size_t)(b * H_ + h) * T_ + t) * HD_;
                if (region < 2) {
                    const float cz = rope[t * 32 + d * 2];
                    const float sz = rope[t * 32 + d * 2 + 1];
                    const float n0 = v0 * cz - v1 * sz;
                    const float n1 = v1 * cz + v0 * sz;
                    dst[base + d] = f2b(n0);
                    dst[base + 16 + d] = f2b(n1);
                } else {
                    dst[base + d] = f2b(v0);
                    dst[base + 16 + d] = f2b(v1);
                }
                dst[base + 32 + d] = f2b(v2);
                dst[base + 48 + d] = f2b(v3);
            }
        }
    } else {
        float* outf = (float*)o0v;
#pragma unroll
        for (int i = 0; i < 4; i++)
#pragma unroll
            for (int r = 0; r < 4; r++) {
                const int m = mBase + wr * 64 + i * 16 + quad * 4 + r;
                const size_t o = (size_t)m * 2048 + nq;
#pragma unroll
                for (int j = 0; j < 4; j++)
                    outf[o + j * 16 + l15] = acc[i][j][r] + bv[j];
            }
    }
}

// ---------------------------------------------------------------------------
// MFMA flash attention (unchanged — verified rounds 3-5).
// ---------------------------------------------------------------------------
#define VT_STR 72

__global__ __launch_bounds__(256) void attn_mfma(const u16* __restrict__ qT,
                                                 const u16* __restrict__ kT,
                                                 const u16* __restrict__ vT,
                                                 u16* __restrict__ ctx) {
    __shared__ __align__(16) u16 Vt[64 * VT_STR];        // V^T: [hd][key]
    __shared__ __align__(16) u16 Pt[4 * 16 * VT_STR];    // per-wave P^T: [q][key]

    const int tid = threadIdx.x;
    const int w = tid >> 6, lane = tid & 63;
    const int quad = lane >> 4, l15 = lane & 15;
    const int qt = 15 - (int)blockIdx.x;   // big tiles dispatch first
    const int bh = blockIdx.y;
    const size_t headBase = (size_t)bh * (T_ * HD_);

    bf16x8 qf[2];
    {
        const u16* qrow = qT + headBase + ((size_t)qt * 64 + w * 16 + l15) * HD_ + quad * 8;
        qf[0] = __builtin_bit_cast(bf16x8, *(const u16x8*)(qrow));
        qf[1] = __builtin_bit_cast(bf16x8, *(const u16x8*)(qrow + 32));
    }

    u16* myPt = &Pt[w * 16 * VT_STR];
    const int vhd = tid & 63, vkb = tid >> 6;
    float m_i = -1e30f, l_i = 0.f;
    floatx4 oacc[4] = {};

    for (int kt = 0; kt <= qt; kt++) {
        const u16* kp = kT + headBase + (size_t)kt * 64 * HD_;
        const u16* vp = vT + headBase + (size_t)kt * 64 * HD_;

        u16 vreg[16];
#pragma unroll
        for (int c = 0; c < 16; c++)
            vreg[c] = vp[(vkb * 16 + c) * HD_ + vhd];

        floatx4 st[4] = {};
#pragma unroll
        for (int mi = 0; mi < 4; mi++) {
            const u16* krow = kp + (mi * 16 + l15) * HD_ + quad * 8;
            const bf16x8 kf0 = __builtin_bit_cast(bf16x8, *(const u16x8*)(krow));
            const bf16x8 kf1 = __builtin_bit_cast(bf16x8, *(const u16x8*)(krow + 32));
            st[mi] = __builtin_amdgcn_mfma_f32_16x16x32_bf16(kf0, qf[0], st[mi], 0, 0, 0);
            st[mi] = __builtin_amdgcn_mfma_f32_16x16x32_bf16(kf1, qf[1], st[mi], 0, 0, 0);
        }

        __syncthreads();
#pragma unroll
        for (int c4 = 0; c4 < 4; c4++) {
            const u16x4 vv = {vreg[c4 * 4], vreg[c4 * 4 + 1], vreg[c4 * 4 + 2], vreg[c4 * 4 + 3]};
            *(u16x4*)&Vt[vhd * VT_STR + vkb * 16 + c4 * 4] = vv;
        }
        __syncthreads();

        float pmax = -1e30f;
#pragma unroll
        for (int mi = 0; mi < 4; mi++)
#pragma unroll
            for (int r = 0; r < 4; r++) {
                float sv = st[mi][r] * 0.125f;
                if (kt == qt && (mi * 16 + quad * 4 + r) > (w * 16 + l15)) sv = -1e30f;
                st[mi][r] = sv;
                pmax = fmaxf(pmax, sv);
            }
        pmax = fmaxf(pmax, __shfl_xor(pmax, 16, 64));
        pmax = fmaxf(pmax, __shfl_xor(pmax, 32, 64));
        const float mnew = fmaxf(m_i, pmax);
        const float alpha = __expf(m_i - mnew);
        m_i = mnew;

        float psum = 0.f;
#pragma unroll
        for (int mi = 0; mi < 4; mi++) {
            u16x4 pk;
#pragma unroll
            for (int r = 0; r < 4; r++) {
                const float p = __expf(st[mi][r] - mnew);
                psum += p;
                pk[r] = f2b(p);
            }
            *(u16x4*)&myPt[l15 * VT_STR + mi * 16 + quad * 4] = pk;
        }
        psum += __shfl_xor(psum, 16, 64);
        psum += __shfl_xor(psum, 32, 64);
        l_i = l_i * alpha + psum;

#pragma unroll
        for (int mi = 0; mi < 4; mi++) oacc[mi] *= alpha;

        bf16x8 pf[2];
        pf[0] = __builtin_bit_cast(bf16x8, *(const u16x8*)&myPt[l15 * VT_STR + quad * 8]);
        pf[1] = __builtin_bit_cast(bf16x8, *(const u16x8*)&myPt[l15 * VT_STR + 32 + quad * 8]);
#pragma unroll
        for (int mi = 0; mi < 4; mi++) {
            const bf16x8 vf0 = __builtin_bit_cast(bf16x8, *(const u16x8*)&Vt[(mi * 16 + l15) * VT_STR + quad * 8]);
            const bf16x8 vf1 = __builtin_bit_cast(bf16x8, *(const u16x8*)&Vt[(mi * 16 + l15) * VT_STR + 32 + quad * 8]);
            oacc[mi] = __builtin_amdgcn_mfma_f32_16x16x32_bf16(vf0, pf[0], oacc[mi], 0, 0, 0);
            oacc[mi] = __builtin_amdgcn_mfma_f32_16x16x32_bf16(vf1, pf[1], oacc[mi], 0, 0, 0);
        }
    }

    const float inv = 1.0f / l_i;
    const int b = bh >> 5, h = bh & 31;
    const int t = qt * 64 + w * 16 + l15;
    u16* cp = ctx + ((size_t)(b * T_ + t)) * C_ + h * HD_;
#pragma unroll
    for (int mi = 0; mi < 4; mi++) {
        const u16x4 ov = {f2b(oacc[mi][0] * inv), f2b(oacc[mi][1] * inv),
                          f2b(oacc[mi][2] * inv), f2b(oacc[mi][3] * inv)};
        *(u16x4*)(cp + mi * 16 + quad * 4) = ov;
    }
}

extern "C" void kernel_launch(void* const* d_in, const int* in_sizes, int n_in,
                              void* d_out, int out_size, void* d_ws, size_t ws_size,
                              hipStream_t stream) {
    const float* x      = (const float*)d_in[0];
    const float* rope   = (const float*)d_in[3];
    const float* Wqkv_w = (const float*)d_in[4];
    const float* Wqkv_b = (const float*)d_in[5];
    const float* out_w  = (const float*)d_in[6];
    const float* out_b  = (const float*)d_in[7];
    float* out = (float*)d_out;

    // ws layout (u16 elems), total 100.7 MB:
    //   xb 8.39M | wqkvb 12.58M | outwb 4.19M | qT 8.39M | kT 8.39M | vT 8.39M
    //   ctx aliases xb (x dead after gemm0)
    const size_t headElems = (size_t)B_ * H_ * T_ * HD_;     // 8388608
    u16* xb    = (u16*)d_ws;
    u16* wqkvb = xb + headElems;
    u16* outwb = wqkvb + 12582912;
    u16* qTp   = outwb + 4194304;
    u16* kTp   = qTp + headElems;
    u16* vTp   = kTp + headElems;
    u16* ctx   = xb;

    convert_bf16<<<dim3(2048), 256, 0, stream>>>(x, xb, 2097152);
    convert_bf16<<<dim3(3072), 256, 0, stream>>>(Wqkv_w, wqkvb, 3145728);
    convert_bf16<<<dim3(1024), 256, 0, stream>>>(out_w, outwb, 1048576);

    gemm_bt<0><<<dim3(48, 32), 256, 0, stream>>>(xb, wqkvb, Wqkv_b, rope, qTp, kTp, vTp);
    attn_mfma<<<dim3(16, 128), 256, 0, stream>>>(qTp, kTp, vTp, ctx);
    gemm_bt<1><<<dim3(16, 32), 256, 0, stream>>>(ctx, outwb, out_b, rope, out, nullptr, nullptr);
}